// Round 1
// baseline (900.542 us; speedup 1.0000x reference)
//
#include <hip/hip_runtime.h>
#include <hip/hip_bf16.h>
#include <math.h>

typedef __bf16 bf16_t;
typedef __bf16 bf16x8 __attribute__((ext_vector_type(8)));
typedef __bf16 bf16x4 __attribute__((ext_vector_type(4)));
typedef float  f32x4  __attribute__((ext_vector_type(4)));

// Problem geometry (fixed): x[4][2048][1024], w1[1024][4096], w2[4096][1024]
#define NROWS 8192   // 4*2048
#define HD    1024
#define DFF   4096

// ---------------- transpose + f32->bf16 convert (w1 -> [DFF][H], w2 -> [H][DFF])
__global__ __launch_bounds__(256) void transpose_to_bf16(
    const float* __restrict__ in, bf16_t* __restrict__ out, int R, int C)
{
  __shared__ float tile[32][33];
  const int bx = blockIdx.x, by = blockIdx.y;
  const int tx = threadIdx.x, ty = threadIdx.y;
  #pragma unroll
  for (int i = ty; i < 32; i += 8)
    tile[i][tx] = in[(size_t)(by*32 + i)*C + bx*32 + tx];
  __syncthreads();
  #pragma unroll
  for (int i = ty; i < 32; i += 8)
    out[(size_t)(bx*32 + i)*R + by*32 + tx] = (bf16_t)tile[tx][i];
}

// ---------------- 1024-pt FFT along h, one row per block, real input
__global__ __launch_bounds__(256) void fft_h_kernel(
    const float* __restrict__ x, float* __restrict__ re, float* __restrict__ im)
{
  __shared__ float sre[1024], sim[1024], twc[512], tws[512];
  const int t = threadIdx.x;
  const size_t row = blockIdx.x;
  const float* xr = x + row * HD;
  for (int k = t; k < 512; k += 256) {
    float sv, cv; sincosf(-6.28318530717958647692f * (float)k * (1.0f/1024.0f), &sv, &cv);
    twc[k] = cv; tws[k] = sv;
  }
  #pragma unroll
  for (int q = 0; q < 4; ++q) sre[t + 256*q] = xr[t + 256*q];
  __syncthreads();
  float rv[4];
  #pragma unroll
  for (int q = 0; q < 4; ++q) rv[q] = sre[__brev((unsigned)(t + 256*q)) >> 22];
  __syncthreads();
  #pragma unroll
  for (int q = 0; q < 4; ++q) { sre[t + 256*q] = rv[q]; sim[t + 256*q] = 0.0f; }
  __syncthreads();
  for (int s = 0; s < 10; ++s) {
    const int half = 1 << s;
    #pragma unroll
    for (int q = 0; q < 2; ++q) {
      const int b  = t + 256*q;
      const int j  = b & (half - 1);
      const int ib = ((b >> s) << (s + 1)) | j;
      const int ti2 = j << (9 - s);
      const float wc = twc[ti2], ws = tws[ti2];
      const float r1 = sre[ib],       i1v = sim[ib];
      const float r2 = sre[ib+half],  i2v = sim[ib+half];
      const float tr = r2*wc - i2v*ws;
      const float ti = r2*ws + i2v*wc;
      sre[ib]      = r1 + tr; sim[ib]      = i1v + ti;
      sre[ib+half] = r1 - tr; sim[ib+half] = i1v - ti;
    }
    __syncthreads();
  }
  #pragma unroll
  for (int q = 0; q < 4; ++q) {
    re[row*HD + t + 256*q] = sre[t + 256*q];
    im[row*HD + t + 256*q] = sim[t + 256*q];
  }
}

// ---------------- 2048-pt FFT along s, complex input, 2 h-columns per block;
// writes y = x + Re(FFT2)
__global__ __launch_bounds__(512) void fft_s_kernel(
    const float* __restrict__ re, const float* __restrict__ im,
    const float* __restrict__ x, float* __restrict__ y)
{
  __shared__ float sre[2048*2], sim[2048*2], twc[1024], tws[1024];
  const int t  = threadIdx.x;
  const int c  = t & 1, sp = t >> 1;        // 256 s-slots x 2 columns
  const int blk   = blockIdx.x;             // 0..2047
  const int batch = blk >> 9;               // 4 batches
  const int h0    = (blk & 511) * 2;
  for (int k = t; k < 1024; k += 512) {
    float sv, cv; sincosf(-6.28318530717958647692f * (float)k * (1.0f/2048.0f), &sv, &cv);
    twc[k] = cv; tws[k] = sv;
  }
  const size_t base = ((size_t)batch * 2048) * HD + h0 + c;
  #pragma unroll
  for (int q = 0; q < 8; ++q) {
    const int i   = sp + 256*q;
    const int src = __brev((unsigned)i) >> 21;   // 11-bit bit reversal
    sre[i*2 + c] = re[base + (size_t)src * HD];
    sim[i*2 + c] = im[base + (size_t)src * HD];
  }
  __syncthreads();
  for (int s = 0; s < 11; ++s) {
    const int half = 1 << s;
    #pragma unroll
    for (int q = 0; q < 4; ++q) {
      const int b  = sp + 256*q;
      const int j  = b & (half - 1);
      const int ib = ((b >> s) << (s + 1)) | j;
      const int ti2 = j << (10 - s);
      const float wc = twc[ti2], ws = tws[ti2];
      const int p1 = ib*2 + c, p2 = (ib + half)*2 + c;
      const float r1 = sre[p1], i1v = sim[p1];
      const float r2 = sre[p2], i2v = sim[p2];
      const float tr = r2*wc - i2v*ws;
      const float ti = r2*ws + i2v*wc;
      sre[p1] = r1 + tr; sim[p1] = i1v + ti;
      sre[p2] = r1 - tr; sim[p2] = i1v - ti;
    }
    __syncthreads();
  }
  #pragma unroll
  for (int q = 0; q < 8; ++q) {
    const int i = sp + 256*q;
    const size_t gi = ((size_t)batch * 2048 + i) * HD + h0 + c;
    y[gi] = x[gi] + sre[i*2 + c];
  }
}

// ---------------- LayerNorm over H=1024, one row per block (256 thr x 4 elems)
template <bool OUT_BF16>
__global__ __launch_bounds__(256) void layernorm_k(
    const float* __restrict__ in, const float* __restrict__ gw,
    const float* __restrict__ gb, bf16_t* __restrict__ ob, float* __restrict__ of)
{
  __shared__ float red[8];
  const size_t row = blockIdx.x;
  const int t = threadIdx.x;
  const float* xr = in + row * HD;
  float4 v = *(const float4*)(xr + t*4);
  float s = v.x + v.y + v.z + v.w;
  #pragma unroll
  for (int o = 32; o > 0; o >>= 1) s += __shfl_xor(s, o);
  if ((t & 63) == 0) red[t >> 6] = s;
  __syncthreads();
  const float mu = (red[0]+red[1]+red[2]+red[3]) * (1.0f/1024.0f);
  const float dx = v.x-mu, dy = v.y-mu, dz = v.z-mu, dw = v.w-mu;
  float sq = dx*dx + dy*dy + dz*dz + dw*dw;
  #pragma unroll
  for (int o = 32; o > 0; o >>= 1) sq += __shfl_xor(sq, o);
  if ((t & 63) == 0) red[4 + (t >> 6)] = sq;
  __syncthreads();
  const float var  = (red[4]+red[5]+red[6]+red[7]) * (1.0f/1024.0f);
  const float rstd = rsqrtf(var + 1e-5f);
  const float4 wv = *(const float4*)(gw + t*4);
  const float4 bv = *(const float4*)(gb + t*4);
  const float o0 = dx*rstd*wv.x + bv.x;
  const float o1 = dy*rstd*wv.y + bv.y;
  const float o2 = dz*rstd*wv.z + bv.z;
  const float o3 = dw*rstd*wv.w + bv.w;
  if constexpr (OUT_BF16) {
    bf16x4 o; o[0]=(bf16_t)o0; o[1]=(bf16_t)o1; o[2]=(bf16_t)o2; o[3]=(bf16_t)o3;
    *(bf16x4*)(ob + row*HD + t*4) = o;
  } else {
    float4 o; o.x=o0; o.y=o1; o.z=o2; o.w=o3;
    *(float4*)(of + row*HD + t*4) = o;
  }
}

// ---------------- bf16 MFMA GEMM: C = A[M][K] * Bt[N][K]^T (+bias, epilogue)
// 128x128 tile, BK=64, 4 waves (2x2 of 64x64), reg-staged LDS with XOR swizzle.
__device__ __forceinline__ float gelu_exact(float v) {
  return 0.5f * v * (1.0f + erff(v * 0.70710678118654752440f));
}

template <bool GELU_BF16_OUT>
__global__ __launch_bounds__(256) void gemm_bf16_kernel(
    const bf16_t* __restrict__ A,     // [M][K]
    const bf16_t* __restrict__ Bt,    // [N][K]  (= B^T, rows are output cols)
    const float*  __restrict__ bias,  // [N]
    const bf16_t* __restrict__ resid, // [M][N]  (only used when !GELU_BF16_OUT)
    bf16_t* __restrict__ outB, float* __restrict__ outF,
    int M, int N, int K)
{
  constexpr int BK = 64;
  __shared__ bf16_t As[128*BK];
  __shared__ bf16_t Bs[128*BK];
  const int tid  = threadIdx.x;
  const int wave = tid >> 6, lane = tid & 63;
  const int wr = wave >> 1, wc = wave & 1;     // 2x2 waves of 64x64
  const int lr  = lane & 15;
  const int lgk = lane >> 4;                   // k-group 0..3 (8 bf16 each)
  const int brow = blockIdx.y * 128, bcol = blockIdx.x * 128;

  // staging decomposition: each thread owns 4 slots of 16B per matrix
  const int srow = tid >> 3;                   // 0..31 (+32q)
  const int sg   = tid & 7;                    // source k-group 0..7
  const int woff = ((sg ^ (srow & 7)) << 3);   // swizzled LDS k-offset (elems)

  const bf16_t* Ab = A  + (size_t)(brow + srow) * K + sg*8;
  const bf16_t* Bb = Bt + (size_t)(bcol + srow) * K + sg*8;

  uint4 pa[4], pb[4];
  #pragma unroll
  for (int q = 0; q < 4; ++q) {
    pa[q] = *(const uint4*)(Ab + (size_t)(32*q) * K);
    pb[q] = *(const uint4*)(Bb + (size_t)(32*q) * K);
  }

  f32x4 acc[4][4] = {};

  for (int k0 = 0; k0 < K; k0 += BK) {
    #pragma unroll
    for (int q = 0; q < 4; ++q) {
      *(uint4*)&As[(srow + 32*q)*BK + woff] = pa[q];
      *(uint4*)&Bs[(srow + 32*q)*BK + woff] = pb[q];
    }
    __syncthreads();
    if (k0 + BK < K) {
      #pragma unroll
      for (int q = 0; q < 4; ++q) {
        pa[q] = *(const uint4*)(Ab + (size_t)(32*q) * K + (k0 + BK));
        pb[q] = *(const uint4*)(Bb + (size_t)(32*q) * K + (k0 + BK));
      }
    }
    #pragma unroll
    for (int ks = 0; ks < 2; ++ks) {
      bf16x8 af[4], bv[4];
      #pragma unroll
      for (int m = 0; m < 4; ++m) {
        const int r  = wr*64 + m*16 + lr;
        const int gk = (lgk + ks*4) ^ (r & 7);
        af[m] = *(const bf16x8*)&As[r*BK + (gk << 3)];
      }
      #pragma unroll
      for (int n = 0; n < 4; ++n) {
        const int r  = wc*64 + n*16 + lr;
        const int gk = (lgk + ks*4) ^ (r & 7);
        bv[n] = *(const bf16x8*)&Bs[r*BK + (gk << 3)];
      }
      #pragma unroll
      for (int m = 0; m < 4; ++m)
        #pragma unroll
        for (int n = 0; n < 4; ++n)
          acc[m][n] = __builtin_amdgcn_mfma_f32_16x16x32_bf16(af[m], bv[n], acc[m][n], 0, 0, 0);
    }
    __syncthreads();
  }

  // epilogue: C/D map (verified): col = lane&15, row = (lane>>4)*4 + j
  const int r4 = (lane >> 4) * 4;
  #pragma unroll
  for (int m = 0; m < 4; ++m) {
    #pragma unroll
    for (int n = 0; n < 4; ++n) {
      const int col = bcol + wc*64 + n*16 + lr;
      const float bval = bias[col];
      #pragma unroll
      for (int j = 0; j < 4; ++j) {
        const int row = brow + wr*64 + m*16 + r4 + j;
        float vv = acc[m][n][j] + bval;
        if constexpr (GELU_BF16_OUT) {
          vv = gelu_exact(vv);
          outB[(size_t)row * N + col] = (bf16_t)vv;
        } else {
          vv += (float)resid[(size_t)row * N + col];
          outF[(size_t)row * N + col] = vv;
        }
      }
    }
  }
}

extern "C" void kernel_launch(void* const* d_in, const int* in_sizes, int n_in,
                              void* d_out, int out_size, void* d_ws, size_t ws_size,
                              hipStream_t stream) {
  const float* x    = (const float*)d_in[0];
  const float* ln1w = (const float*)d_in[1];
  const float* ln1b = (const float*)d_in[2];
  const float* ln2w = (const float*)d_in[3];
  const float* ln2b = (const float*)d_in[4];
  const float* w1   = (const float*)d_in[5];
  const float* b1   = (const float*)d_in[6];
  const float* w2   = (const float*)d_in[7];
  const float* b2   = (const float*)d_in[8];
  float* out = (float*)d_out;

  // workspace layout (128 MB):
  //  [0,32M)   re        -> later reused as hgelu (with im): hgelu = [0,64M)
  //  [32M,64M) im
  //  [64M,96M) y   (fp32 x + fourier)
  //  [96M,112M) xn (bf16 LN1 output, also FFN residual)
  //  [112M,120M) w1b (bf16, transposed: [DFF][H])
  //  [120M,128M) w2b (bf16, transposed: [H][DFF])
  char* ws = (char*)d_ws;
  float*  re  = (float*)(ws + 0);
  float*  im  = (float*)(ws + (32u << 20));
  float*  y   = (float*)(ws + (64u << 20));
  bf16_t* xn  = (bf16_t*)(ws + (96u << 20));
  bf16_t* w1b = (bf16_t*)(ws + (112u << 20));
  bf16_t* w2b = (bf16_t*)(ws + (120u << 20));
  bf16_t* hg  = (bf16_t*)(ws + 0);            // [NROWS][DFF] bf16, reuses re/im

  // weight transposes + bf16 conversion
  transpose_to_bf16<<<dim3(DFF/32, HD/32), dim3(32, 8), 0, stream>>>(w1, w1b, HD, DFF);
  transpose_to_bf16<<<dim3(HD/32, DFF/32), dim3(32, 8), 0, stream>>>(w2, w2b, DFF, HD);

  // 2D FFT (real part) + residual
  fft_h_kernel<<<NROWS, 256, 0, stream>>>(x, re, im);
  fft_s_kernel<<<2048, 512, 0, stream>>>(re, im, x, y);

  // LN1 -> bf16
  layernorm_k<true><<<NROWS, 256, 0, stream>>>(y, ln1w, ln1b, xn, nullptr);

  // FFN
  gemm_bf16_kernel<true><<<dim3(DFF/128, NROWS/128), 256, 0, stream>>>(
      xn, w1b, b1, nullptr, hg, nullptr, NROWS, DFF, HD);
  gemm_bf16_kernel<false><<<dim3(HD/128, NROWS/128), 256, 0, stream>>>(
      hg, w2b, b2, xn, nullptr, out, NROWS, HD, DFF);

  // LN2 in place on d_out
  layernorm_k<false><<<NROWS, 256, 0, stream>>>(out, ln2w, ln2b, nullptr, out);
}

// Round 2
// 456.369 us; speedup vs baseline: 1.9733x; 1.9733x over previous
//
#include <hip/hip_runtime.h>
#include <hip/hip_bf16.h>
#include <math.h>

typedef __bf16 bf16_t;
typedef __bf16 bf16x8 __attribute__((ext_vector_type(8)));
typedef __bf16 bf16x4 __attribute__((ext_vector_type(4)));
typedef float  f32x4  __attribute__((ext_vector_type(4)));

// Problem geometry (fixed): x[4][2048][1024], w1[1024][4096], w2[4096][1024]
#define NROWS 8192   // 4*2048
#define HD    1024
#define DFF   4096

typedef __attribute__((address_space(1))) const void* gas_cptr;
typedef __attribute__((address_space(3))) void* las_ptr;

__device__ __forceinline__ void gload_lds16(const void* g, void* l) {
  // async global->LDS, 16B per lane; LDS dest = wave-uniform base + lane*16
  __builtin_amdgcn_global_load_lds((gas_cptr)g, (las_ptr)l, 16, 0, 0);
}

// ---------------- transpose + f32->bf16 convert (w1 -> [DFF][H], w2 -> [H][DFF])
__global__ __launch_bounds__(256) void transpose_to_bf16(
    const float* __restrict__ in, bf16_t* __restrict__ out, int R, int C)
{
  __shared__ float tile[32][33];
  const int bx = blockIdx.x, by = blockIdx.y;
  const int tx = threadIdx.x, ty = threadIdx.y;
  #pragma unroll
  for (int i = ty; i < 32; i += 8)
    tile[i][tx] = in[(size_t)(by*32 + i)*C + bx*32 + tx];
  __syncthreads();
  #pragma unroll
  for (int i = ty; i < 32; i += 8)
    out[(size_t)(bx*32 + i)*R + by*32 + tx] = (bf16_t)tile[tx][i];
}

// ---------------- 1024-pt FFT along h, one row per block, real input
__global__ __launch_bounds__(256) void fft_h_kernel(
    const float* __restrict__ x, float* __restrict__ re, float* __restrict__ im)
{
  __shared__ float sre[1024], sim[1024], twc[512], tws[512];
  const int t = threadIdx.x;
  const size_t row = blockIdx.x;
  const float* xr = x + row * HD;
  for (int k = t; k < 512; k += 256) {
    float sv, cv; sincosf(-6.28318530717958647692f * (float)k * (1.0f/1024.0f), &sv, &cv);
    twc[k] = cv; tws[k] = sv;
  }
  #pragma unroll
  for (int q = 0; q < 4; ++q) sre[t + 256*q] = xr[t + 256*q];
  __syncthreads();
  float rv[4];
  #pragma unroll
  for (int q = 0; q < 4; ++q) rv[q] = sre[__brev((unsigned)(t + 256*q)) >> 22];
  __syncthreads();
  #pragma unroll
  for (int q = 0; q < 4; ++q) { sre[t + 256*q] = rv[q]; sim[t + 256*q] = 0.0f; }
  __syncthreads();
  for (int s = 0; s < 10; ++s) {
    const int half = 1 << s;
    #pragma unroll
    for (int q = 0; q < 2; ++q) {
      const int b  = t + 256*q;
      const int j  = b & (half - 1);
      const int ib = ((b >> s) << (s + 1)) | j;
      const int ti2 = j << (9 - s);
      const float wc = twc[ti2], ws = tws[ti2];
      const float r1 = sre[ib],       i1v = sim[ib];
      const float r2 = sre[ib+half],  i2v = sim[ib+half];
      const float tr = r2*wc - i2v*ws;
      const float ti = r2*ws + i2v*wc;
      sre[ib]      = r1 + tr; sim[ib]      = i1v + ti;
      sre[ib+half] = r1 - tr; sim[ib+half] = i1v - ti;
    }
    __syncthreads();
  }
  #pragma unroll
  for (int q = 0; q < 4; ++q) {
    re[row*HD + t + 256*q] = sre[t + 256*q];
    im[row*HD + t + 256*q] = sim[t + 256*q];
  }
}

// ---------------- 2048-pt FFT along s, complex input, 2 h-columns per block;
// writes y = x + Re(FFT2)
__global__ __launch_bounds__(512) void fft_s_kernel(
    const float* __restrict__ re, const float* __restrict__ im,
    const float* __restrict__ x, float* __restrict__ y)
{
  __shared__ float sre[2048*2], sim[2048*2], twc[1024], tws[1024];
  const int t  = threadIdx.x;
  const int c  = t & 1, sp = t >> 1;        // 256 s-slots x 2 columns
  const int blk   = blockIdx.x;             // 0..2047
  const int batch = blk >> 9;               // 4 batches
  const int h0    = (blk & 511) * 2;
  for (int k = t; k < 1024; k += 512) {
    float sv, cv; sincosf(-6.28318530717958647692f * (float)k * (1.0f/2048.0f), &sv, &cv);
    twc[k] = cv; tws[k] = sv;
  }
  const size_t base = ((size_t)batch * 2048) * HD + h0 + c;
  #pragma unroll
  for (int q = 0; q < 8; ++q) {
    const int i   = sp + 256*q;
    const int src = __brev((unsigned)i) >> 21;   // 11-bit bit reversal
    sre[i*2 + c] = re[base + (size_t)src * HD];
    sim[i*2 + c] = im[base + (size_t)src * HD];
  }
  __syncthreads();
  for (int s = 0; s < 11; ++s) {
    const int half = 1 << s;
    #pragma unroll
    for (int q = 0; q < 4; ++q) {
      const int b  = sp + 256*q;
      const int j  = b & (half - 1);
      const int ib = ((b >> s) << (s + 1)) | j;
      const int ti2 = j << (10 - s);
      const float wc = twc[ti2], ws = tws[ti2];
      const int p1 = ib*2 + c, p2 = (ib + half)*2 + c;
      const float r1 = sre[p1], i1v = sim[p1];
      const float r2 = sre[p2], i2v = sim[p2];
      const float tr = r2*wc - i2v*ws;
      const float ti = r2*ws + i2v*wc;
      sre[p1] = r1 + tr; sim[p1] = i1v + ti;
      sre[p2] = r1 - tr; sim[p2] = i1v - ti;
    }
    __syncthreads();
  }
  #pragma unroll
  for (int q = 0; q < 8; ++q) {
    const int i = sp + 256*q;
    const size_t gi = ((size_t)batch * 2048 + i) * HD + h0 + c;
    y[gi] = x[gi] + sre[i*2 + c];
  }
}

// ---------------- LayerNorm over H=1024, one row per block (256 thr x 4 elems)
template <bool OUT_BF16>
__global__ __launch_bounds__(256) void layernorm_k(
    const float* __restrict__ in, const float* __restrict__ gw,
    const float* __restrict__ gb, bf16_t* __restrict__ ob, float* __restrict__ of)
{
  __shared__ float red[8];
  const size_t row = blockIdx.x;
  const int t = threadIdx.x;
  const float* xr = in + row * HD;
  float4 v = *(const float4*)(xr + t*4);
  float s = v.x + v.y + v.z + v.w;
  #pragma unroll
  for (int o = 32; o > 0; o >>= 1) s += __shfl_xor(s, o);
  if ((t & 63) == 0) red[t >> 6] = s;
  __syncthreads();
  const float mu = (red[0]+red[1]+red[2]+red[3]) * (1.0f/1024.0f);
  const float dx = v.x-mu, dy = v.y-mu, dz = v.z-mu, dw = v.w-mu;
  float sq = dx*dx + dy*dy + dz*dz + dw*dw;
  #pragma unroll
  for (int o = 32; o > 0; o >>= 1) sq += __shfl_xor(sq, o);
  if ((t & 63) == 0) red[4 + (t >> 6)] = sq;
  __syncthreads();
  const float var  = (red[4]+red[5]+red[6]+red[7]) * (1.0f/1024.0f);
  const float rstd = rsqrtf(var + 1e-5f);
  const float4 wv = *(const float4*)(gw + t*4);
  const float4 bv = *(const float4*)(gb + t*4);
  const float o0 = dx*rstd*wv.x + bv.x;
  const float o1 = dy*rstd*wv.y + bv.y;
  const float o2 = dz*rstd*wv.z + bv.z;
  const float o3 = dw*rstd*wv.w + bv.w;
  if constexpr (OUT_BF16) {
    bf16x4 o; o[0]=(bf16_t)o0; o[1]=(bf16_t)o1; o[2]=(bf16_t)o2; o[3]=(bf16_t)o3;
    *(bf16x4*)(ob + row*HD + t*4) = o;
  } else {
    float4 o; o.x=o0; o.y=o1; o.z=o2; o.w=o3;
    *(float4*)(of + row*HD + t*4) = o;
  }
}

// ---------------- bf16 MFMA GEMM: C = A[M][K] * Bt[N][K]^T (+bias, epilogue)
// m97 structure: 128x128 tile, BK=64, 4 waves (2x2 of 64x64),
// global_load_lds width=16 staging (linear LDS dest, pre-swizzled global src),
// XOR-swizzled ds_read (~2-way conflicts), swapped-operand MFMA so the
// epilogue stores 4 consecutive columns per lane (vectorized).
__device__ __forceinline__ float gelu_exact(float v) {
  return 0.5f * v * (1.0f + erff(v * 0.70710678118654752440f));
}

template <bool GELU_BF16_OUT>
__global__ __launch_bounds__(256) void gemm_bf16_kernel(
    const bf16_t* __restrict__ A,     // [M][K]
    const bf16_t* __restrict__ Bt,    // [N][K]  (= B^T, rows are output cols)
    const float*  __restrict__ bias,  // [N]
    const bf16_t* __restrict__ resid, // [M][N]  (only used when !GELU_BF16_OUT)
    bf16_t* __restrict__ outB, float* __restrict__ outF,
    int M, int N, int K, int gx)
{
  constexpr int BK = 64;
  __shared__ bf16_t As[128*BK];
  __shared__ bf16_t Bs[128*BK];
  const int tid  = threadIdx.x;
  const int wave = tid >> 6, lane = tid & 63;
  const int wr = wave >> 1, wc = wave & 1;     // 2x2 waves of 64x64
  const int lr  = lane & 15;
  const int lkg = lane >> 4;                   // k-group 0..3 (8 bf16 each)

  // XCD-aware bijective swizzle (grid % 8 == 0 for both GEMMs)
  const int nwg = gridDim.x;
  const int sid = (blockIdx.x & 7) * (nwg >> 3) + (blockIdx.x >> 3);
  const int bx = sid % gx, by = sid / gx;
  const int brow = by * 128, bcol = bx * 128;

  // staging: chunk (wave*4+q) covers tile-rows [chunk*8, chunk*8+8).
  // LDS dest is linear (lane*16B); source k-group is pre-swizzled so that
  // LDS[row][g] holds global k-group g ^ (row&7)  (involution, rule #21).
  const int rloc = lane >> 3;                  // row within 8-row chunk
  const int sgrp = (lane & 7) ^ rloc;          // pre-swizzled source k-group
  const bf16_t* Ag = A  + (size_t)(brow + wave*32 + rloc) * K + sgrp * 8;
  const bf16_t* Bg = Bt + (size_t)(bcol + wave*32 + rloc) * K + sgrp * 8;

  f32x4 acc[4][4] = {};

  for (int k0 = 0; k0 < K; k0 += BK) {
    #pragma unroll
    for (int q = 0; q < 4; ++q) {
      gload_lds16(Ag + (size_t)(q*8)*K + k0, &As[(wave*4 + q) * 512]);
      gload_lds16(Bg + (size_t)(q*8)*K + k0, &Bs[(wave*4 + q) * 512]);
    }
    __syncthreads();   // compiler drains vmcnt(0) before barrier

    #pragma unroll
    for (int ks = 0; ks < 2; ++ks) {
      const int g = (lkg + ks*4) ^ (lr & 7);   // swizzled k-group on read
      bf16x8 af[4], bv[4];
      #pragma unroll
      for (int m = 0; m < 4; ++m)
        af[m] = *(const bf16x8*)&As[(wr*64 + m*16 + lr)*BK + g*8];
      #pragma unroll
      for (int n = 0; n < 4; ++n)
        bv[n] = *(const bf16x8*)&Bs[(wc*64 + n*16 + lr)*BK + g*8];
      #pragma unroll
      for (int m = 0; m < 4; ++m)
        #pragma unroll
        for (int n = 0; n < 4; ++n)
          // swapped operands: acc[m][n][j] = C[row = m*16+lr][col = n*16+lkg*4+j]
          acc[m][n] = __builtin_amdgcn_mfma_f32_16x16x32_bf16(bv[n], af[m], acc[m][n], 0, 0, 0);
    }
    __syncthreads();
  }

  // epilogue: lane holds 4 consecutive columns of one row per fragment
  #pragma unroll
  for (int m = 0; m < 4; ++m) {
    const int row = brow + wr*64 + m*16 + lr;
    #pragma unroll
    for (int n = 0; n < 4; ++n) {
      const int col = bcol + wc*64 + n*16 + lkg*4;
      const float4 bv4 = *(const float4*)(bias + col);
      float v0 = acc[m][n][0] + bv4.x;
      float v1 = acc[m][n][1] + bv4.y;
      float v2 = acc[m][n][2] + bv4.z;
      float v3 = acc[m][n][3] + bv4.w;
      if constexpr (GELU_BF16_OUT) {
        bf16x4 o;
        o[0] = (bf16_t)gelu_exact(v0); o[1] = (bf16_t)gelu_exact(v1);
        o[2] = (bf16_t)gelu_exact(v2); o[3] = (bf16_t)gelu_exact(v3);
        *(bf16x4*)(outB + (size_t)row * N + col) = o;
      } else {
        bf16x4 rr = *(const bf16x4*)(resid + (size_t)row * N + col);
        float4 o;
        o.x = v0 + (float)rr[0]; o.y = v1 + (float)rr[1];
        o.z = v2 + (float)rr[2]; o.w = v3 + (float)rr[3];
        *(float4*)(outF + (size_t)row * N + col) = o;
      }
    }
  }
}

extern "C" void kernel_launch(void* const* d_in, const int* in_sizes, int n_in,
                              void* d_out, int out_size, void* d_ws, size_t ws_size,
                              hipStream_t stream) {
  const float* x    = (const float*)d_in[0];
  const float* ln1w = (const float*)d_in[1];
  const float* ln1b = (const float*)d_in[2];
  const float* ln2w = (const float*)d_in[3];
  const float* ln2b = (const float*)d_in[4];
  const float* w1   = (const float*)d_in[5];
  const float* b1   = (const float*)d_in[6];
  const float* w2   = (const float*)d_in[7];
  const float* b2   = (const float*)d_in[8];
  float* out = (float*)d_out;

  // workspace layout (128 MB):
  //  [0,32M)   re        -> later reused as hgelu (with im): hgelu = [0,64M)
  //  [32M,64M) im
  //  [64M,96M) y   (fp32 x + fourier)
  //  [96M,112M) xn (bf16 LN1 output, also FFN residual)
  //  [112M,120M) w1b (bf16, transposed: [DFF][H])
  //  [120M,128M) w2b (bf16, transposed: [H][DFF])
  char* ws = (char*)d_ws;
  float*  re  = (float*)(ws + 0);
  float*  im  = (float*)(ws + (32u << 20));
  float*  y   = (float*)(ws + (64u << 20));
  bf16_t* xn  = (bf16_t*)(ws + (96u << 20));
  bf16_t* w1b = (bf16_t*)(ws + (112u << 20));
  bf16_t* w2b = (bf16_t*)(ws + (120u << 20));
  bf16_t* hg  = (bf16_t*)(ws + 0);            // [NROWS][DFF] bf16, reuses re/im

  // weight transposes + bf16 conversion
  transpose_to_bf16<<<dim3(DFF/32, HD/32), dim3(32, 8), 0, stream>>>(w1, w1b, HD, DFF);
  transpose_to_bf16<<<dim3(HD/32, DFF/32), dim3(32, 8), 0, stream>>>(w2, w2b, DFF, HD);

  // 2D FFT (real part) + residual
  fft_h_kernel<<<NROWS, 256, 0, stream>>>(x, re, im);
  fft_s_kernel<<<2048, 512, 0, stream>>>(re, im, x, y);

  // LN1 -> bf16
  layernorm_k<true><<<NROWS, 256, 0, stream>>>(y, ln1w, ln1b, xn, nullptr);

  // FFN  (1D grids, XCD-swizzled inside the kernel)
  gemm_bf16_kernel<true><<<(DFF/128)*(NROWS/128), 256, 0, stream>>>(
      xn, w1b, b1, nullptr, hg, nullptr, NROWS, DFF, HD, DFF/128);
  gemm_bf16_kernel<false><<<(HD/128)*(NROWS/128), 256, 0, stream>>>(
      hg, w2b, b2, xn, nullptr, out, NROWS, HD, DFF, HD/128);

  // LN2 in place on d_out
  layernorm_k<false><<<NROWS, 256, 0, stream>>>(out, ln2w, ln2b, nullptr, out);
}

// Round 3
// 332.117 us; speedup vs baseline: 2.7115x; 1.3741x over previous
//
#include <hip/hip_runtime.h>
#include <hip/hip_bf16.h>
#include <math.h>

typedef __bf16 bf16_t;
typedef __bf16 bf16x8 __attribute__((ext_vector_type(8)));
typedef __bf16 bf16x4 __attribute__((ext_vector_type(4)));
typedef float  f32x4  __attribute__((ext_vector_type(4)));

// Problem geometry (fixed): x[4][2048][1024], w1[1024][4096], w2[4096][1024]
#define NROWS 8192   // 4*2048
#define HD    1024
#define DFF   4096
#define HKEEP 544    // h-columns materialized (Hermitian: only h<=512 independent)

typedef __attribute__((address_space(1))) const void* gas_cptr;
typedef __attribute__((address_space(3))) void* las_ptr;

__device__ __forceinline__ void gload_lds16(const void* g, void* l) {
  __builtin_amdgcn_global_load_lds((gas_cptr)g, (las_ptr)l, 16, 0, 0);
}

// ---------------- transpose + f32->bf16 convert (w1 -> [DFF][H], w2 -> [H][DFF])
__global__ __launch_bounds__(256) void transpose_to_bf16(
    const float* __restrict__ in, bf16_t* __restrict__ out, int R, int C)
{
  __shared__ float tile[32][33];
  const int bx = blockIdx.x, by = blockIdx.y;
  const int tx = threadIdx.x, ty = threadIdx.y;
  #pragma unroll
  for (int i = ty; i < 32; i += 8)
    tile[i][tx] = in[(size_t)(by*32 + i)*C + bx*32 + tx];
  __syncthreads();
  #pragma unroll
  for (int i = ty; i < 32; i += 8)
    out[(size_t)(bx*32 + i)*R + by*32 + tx] = (bf16_t)tile[tx][i];
}

// ---------------- 1024-pt FFT along h, one row per block, real input.
// Writes only h < HKEEP columns (Hermitian symmetry supplies the rest).
__global__ __launch_bounds__(256) void fft_h_kernel(
    const float* __restrict__ x, float* __restrict__ re, float* __restrict__ im)
{
  __shared__ float sre[1024], sim[1024], twc[512], tws[512];
  const int t = threadIdx.x;
  const size_t row = blockIdx.x;
  const float* xr = x + row * HD;
  for (int k = t; k < 512; k += 256) {
    float sv, cv; sincosf(-6.28318530717958647692f * (float)k * (1.0f/1024.0f), &sv, &cv);
    twc[k] = cv; tws[k] = sv;
  }
  #pragma unroll
  for (int q = 0; q < 4; ++q) sre[t + 256*q] = xr[t + 256*q];
  __syncthreads();
  float rv[4];
  #pragma unroll
  for (int q = 0; q < 4; ++q) rv[q] = sre[__brev((unsigned)(t + 256*q)) >> 22];
  __syncthreads();
  #pragma unroll
  for (int q = 0; q < 4; ++q) { sre[t + 256*q] = rv[q]; sim[t + 256*q] = 0.0f; }
  __syncthreads();
  for (int s = 0; s < 10; ++s) {
    const int half = 1 << s;
    #pragma unroll
    for (int q = 0; q < 2; ++q) {
      const int b  = t + 256*q;
      const int j  = b & (half - 1);
      const int ib = ((b >> s) << (s + 1)) | j;
      const int ti2 = j << (9 - s);
      const float wc = twc[ti2], ws = tws[ti2];
      const float r1 = sre[ib],       i1v = sim[ib];
      const float r2 = sre[ib+half],  i2v = sim[ib+half];
      const float tr = r2*wc - i2v*ws;
      const float ti = r2*ws + i2v*wc;
      sre[ib]      = r1 + tr; sim[ib]      = i1v + ti;
      sre[ib+half] = r1 - tr; sim[ib+half] = i1v - ti;
    }
    __syncthreads();
  }
  #pragma unroll
  for (int q = 0; q < 4; ++q) {
    const int idx = t + 256*q;
    if (idx < HKEEP) {
      re[row*HD + idx] = sre[idx];
      im[row*HD + idx] = sim[idx];
    }
  }
}

// ---------------- tiled transpose of re,im: [8192][1024] -> [HKEEP][8192]
__global__ __launch_bounds__(256) void transpose2_f32(
    const float* __restrict__ re, const float* __restrict__ im,
    float* __restrict__ reT, float* __restrict__ imT)
{
  __shared__ float t0[32][33], t1[32][33];
  const int h0 = blockIdx.x * 32;   // < HKEEP
  const int b0 = blockIdx.y * 32;
  const int tx = threadIdx.x, ty = threadIdx.y;
  #pragma unroll
  for (int i = ty; i < 32; i += 8) {
    t0[i][tx] = re[(size_t)(b0+i)*HD + h0+tx];
    t1[i][tx] = im[(size_t)(b0+i)*HD + h0+tx];
  }
  __syncthreads();
  #pragma unroll
  for (int i = ty; i < 32; i += 8) {
    reT[(size_t)(h0+i)*NROWS + b0+tx] = t0[tx][i];
    imT[(size_t)(h0+i)*NROWS + b0+tx] = t1[tx][i];
  }
}

// ---------------- 2048-pt FFT along s, one (h, batch) column per block.
// Reads contiguous rows of reT/imT; writes real part only, coalesced.
__global__ __launch_bounds__(256) void fft_s_col(
    const float* __restrict__ reT, const float* __restrict__ imT,
    float* __restrict__ fT)
{
  __shared__ float sre[2048], sim[2048], twc[1024], tws[1024];
  const int t = threadIdx.x;
  const int h = blockIdx.x;           // 0..512
  const int batch = blockIdx.y;       // 0..3
  const size_t base = (size_t)h * NROWS + batch * 2048;
  for (int k = t; k < 1024; k += 256) {
    float sv, cv; sincosf(-6.28318530717958647692f * (float)k * (1.0f/2048.0f), &sv, &cv);
    twc[k] = cv; tws[k] = sv;
  }
  #pragma unroll
  for (int q = 0; q < 8; ++q) {
    const int i = t + 256*q;
    const int src = __brev((unsigned)i) >> 21;   // 11-bit bit reversal
    sre[i] = reT[base + src];
    sim[i] = imT[base + src];
  }
  __syncthreads();
  for (int s = 0; s < 11; ++s) {
    const int half = 1 << s;
    #pragma unroll
    for (int q = 0; q < 4; ++q) {
      const int b  = t + 256*q;
      const int j  = b & (half - 1);
      const int ib = ((b >> s) << (s + 1)) | j;
      const int ti2 = j << (10 - s);
      const float wc = twc[ti2], ws = tws[ti2];
      const float r1 = sre[ib],       i1v = sim[ib];
      const float r2 = sre[ib+half],  i2v = sim[ib+half];
      const float tr = r2*wc - i2v*ws;
      const float ti = r2*ws + i2v*wc;
      sre[ib]      = r1 + tr; sim[ib]      = i1v + ti;
      sre[ib+half] = r1 - tr; sim[ib+half] = i1v - ti;
    }
    __syncthreads();
  }
  #pragma unroll
  for (int q = 0; q < 8; ++q) {
    const int i = t + 256*q;
    fT[base + i] = sre[i];
  }
}

// ---------------- untranspose + Hermitian mirror + residual add:
// y[bs][h] = x[bs][h] + (h<=512 ? fT[h][bs] : fT[1024-h][batch*2048 + (2048-s)%2048])
__global__ __launch_bounds__(256) void umadd_kernel(
    const float* __restrict__ fT, const float* __restrict__ x,
    float* __restrict__ y)
{
  __shared__ float tile[32][33];
  const int h0 = blockIdx.x * 32;
  const int b0 = blockIdx.y * 32;
  const int tx = threadIdx.x, ty = threadIdx.y;
  const int batch = b0 >> 11;          // uniform per block (32 | 2048)
  const int s0    = b0 & 2047;
  #pragma unroll
  for (int i = ty; i < 32; i += 8) {
    const int h = h0 + i;
    float v;
    if (h <= 512) {
      v = fT[(size_t)h * NROWS + b0 + tx];
    } else {
      const int sp = (2048 - (s0 + tx)) & 2047;
      v = fT[(size_t)(1024 - h) * NROWS + (batch << 11) + sp];
    }
    tile[i][tx] = v;
  }
  __syncthreads();
  #pragma unroll
  for (int i = ty; i < 32; i += 8) {
    const size_t gi = (size_t)(b0+i)*HD + h0+tx;
    y[gi] = x[gi] + tile[tx][i];
  }
}

// ---------------- LayerNorm over H=1024, one row per block (256 thr x 4 elems)
template <bool OUT_BF16>
__global__ __launch_bounds__(256) void layernorm_k(
    const float* __restrict__ in, const float* __restrict__ gw,
    const float* __restrict__ gb, bf16_t* __restrict__ ob, float* __restrict__ of)
{
  __shared__ float red[8];
  const size_t row = blockIdx.x;
  const int t = threadIdx.x;
  const float* xr = in + row * HD;
  float4 v = *(const float4*)(xr + t*4);
  float s = v.x + v.y + v.z + v.w;
  #pragma unroll
  for (int o = 32; o > 0; o >>= 1) s += __shfl_xor(s, o);
  if ((t & 63) == 0) red[t >> 6] = s;
  __syncthreads();
  const float mu = (red[0]+red[1]+red[2]+red[3]) * (1.0f/1024.0f);
  const float dx = v.x-mu, dy = v.y-mu, dz = v.z-mu, dw = v.w-mu;
  float sq = dx*dx + dy*dy + dz*dz + dw*dw;
  #pragma unroll
  for (int o = 32; o > 0; o >>= 1) sq += __shfl_xor(sq, o);
  if ((t & 63) == 0) red[4 + (t >> 6)] = sq;
  __syncthreads();
  const float var  = (red[4]+red[5]+red[6]+red[7]) * (1.0f/1024.0f);
  const float rstd = rsqrtf(var + 1e-5f);
  const float4 wv = *(const float4*)(gw + t*4);
  const float4 bv = *(const float4*)(gb + t*4);
  const float o0 = dx*rstd*wv.x + bv.x;
  const float o1 = dy*rstd*wv.y + bv.y;
  const float o2 = dz*rstd*wv.z + bv.z;
  const float o3 = dw*rstd*wv.w + bv.w;
  if constexpr (OUT_BF16) {
    bf16x4 o; o[0]=(bf16_t)o0; o[1]=(bf16_t)o1; o[2]=(bf16_t)o2; o[3]=(bf16_t)o3;
    *(bf16x4*)(ob + row*HD + t*4) = o;
  } else {
    float4 o; o.x=o0; o.y=o1; o.z=o2; o.w=o3;
    *(float4*)(of + row*HD + t*4) = o;
  }
}

// ---------------- bf16 MFMA GEMM: C = A[M][K] * Bt[N][K]^T (+bias, epilogue)
__device__ __forceinline__ float gelu_exact(float v) {
  return 0.5f * v * (1.0f + erff(v * 0.70710678118654752440f));
}

template <bool GELU_BF16_OUT>
__global__ __launch_bounds__(256) void gemm_bf16_kernel(
    const bf16_t* __restrict__ A,     // [M][K]
    const bf16_t* __restrict__ Bt,    // [N][K]  (= B^T, rows are output cols)
    const float*  __restrict__ bias,  // [N]
    const bf16_t* __restrict__ resid, // [M][N]  (only used when !GELU_BF16_OUT)
    bf16_t* __restrict__ outB, float* __restrict__ outF,
    int M, int N, int K, int gx)
{
  constexpr int BK = 64;
  __shared__ bf16_t As[128*BK];
  __shared__ bf16_t Bs[128*BK];
  const int tid  = threadIdx.x;
  const int wave = tid >> 6, lane = tid & 63;
  const int wr = wave >> 1, wc = wave & 1;     // 2x2 waves of 64x64
  const int lr  = lane & 15;
  const int lkg = lane >> 4;                   // k-group 0..3 (8 bf16 each)

  // XCD-aware bijective swizzle (grid % 8 == 0 for both GEMMs)
  const int nwg = gridDim.x;
  const int sid = (blockIdx.x & 7) * (nwg >> 3) + (blockIdx.x >> 3);
  const int bx = sid % gx, by = sid / gx;
  const int brow = by * 128, bcol = bx * 128;

  const int rloc = lane >> 3;                  // row within 8-row chunk
  const int sgrp = (lane & 7) ^ rloc;          // pre-swizzled source k-group
  const bf16_t* Ag = A  + (size_t)(brow + wave*32 + rloc) * K + sgrp * 8;
  const bf16_t* Bg = Bt + (size_t)(bcol + wave*32 + rloc) * K + sgrp * 8;

  f32x4 acc[4][4] = {};

  for (int k0 = 0; k0 < K; k0 += BK) {
    #pragma unroll
    for (int q = 0; q < 4; ++q) {
      gload_lds16(Ag + (size_t)(q*8)*K + k0, &As[(wave*4 + q) * 512]);
      gload_lds16(Bg + (size_t)(q*8)*K + k0, &Bs[(wave*4 + q) * 512]);
    }
    __syncthreads();

    #pragma unroll
    for (int ks = 0; ks < 2; ++ks) {
      const int g = (lkg + ks*4) ^ (lr & 7);   // swizzled k-group on read
      bf16x8 af[4], bv[4];
      #pragma unroll
      for (int m = 0; m < 4; ++m)
        af[m] = *(const bf16x8*)&As[(wr*64 + m*16 + lr)*BK + g*8];
      #pragma unroll
      for (int n = 0; n < 4; ++n)
        bv[n] = *(const bf16x8*)&Bs[(wc*64 + n*16 + lr)*BK + g*8];
      #pragma unroll
      for (int m = 0; m < 4; ++m)
        #pragma unroll
        for (int n = 0; n < 4; ++n)
          acc[m][n] = __builtin_amdgcn_mfma_f32_16x16x32_bf16(bv[n], af[m], acc[m][n], 0, 0, 0);
    }
    __syncthreads();
  }

  #pragma unroll
  for (int m = 0; m < 4; ++m) {
    const int row = brow + wr*64 + m*16 + lr;
    #pragma unroll
    for (int n = 0; n < 4; ++n) {
      const int col = bcol + wc*64 + n*16 + lkg*4;
      const float4 bv4 = *(const float4*)(bias + col);
      float v0 = acc[m][n][0] + bv4.x;
      float v1 = acc[m][n][1] + bv4.y;
      float v2 = acc[m][n][2] + bv4.z;
      float v3 = acc[m][n][3] + bv4.w;
      if constexpr (GELU_BF16_OUT) {
        bf16x4 o;
        o[0] = (bf16_t)gelu_exact(v0); o[1] = (bf16_t)gelu_exact(v1);
        o[2] = (bf16_t)gelu_exact(v2); o[3] = (bf16_t)gelu_exact(v3);
        *(bf16x4*)(outB + (size_t)row * N + col) = o;
      } else {
        bf16x4 rr = *(const bf16x4*)(resid + (size_t)row * N + col);
        float4 o;
        o.x = v0 + (float)rr[0]; o.y = v1 + (float)rr[1];
        o.z = v2 + (float)rr[2]; o.w = v3 + (float)rr[3];
        *(float4*)(outF + (size_t)row * N + col) = o;
      }
    }
  }
}

extern "C" void kernel_launch(void* const* d_in, const int* in_sizes, int n_in,
                              void* d_out, int out_size, void* d_ws, size_t ws_size,
                              hipStream_t stream) {
  const float* x    = (const float*)d_in[0];
  const float* ln1w = (const float*)d_in[1];
  const float* ln1b = (const float*)d_in[2];
  const float* ln2w = (const float*)d_in[3];
  const float* ln2b = (const float*)d_in[4];
  const float* w1   = (const float*)d_in[5];
  const float* b1   = (const float*)d_in[6];
  const float* w2   = (const float*)d_in[7];
  const float* b2   = (const float*)d_in[8];
  float* out = (float*)d_out;

  // workspace layout (exactly 128 MB peak, lifetime-checked):
  //  w1b [0,8M)  w2b [8M,16M)                       (steps 1..8)
  //  re  [16M,48M)  im [48M,80M)                    (steps 2-3)
  //  reT [80M,97.83M) imT [98M,115.83M)             (steps 3-4)
  //  fT  [16M,32.81M)   (reuses re; 513 rows)       (steps 4-5)
  //  y   [33M,65M)      (reuses re/im tail)         (steps 5-6)
  //  xn  [16M,32M)      (reuses fT region)          (steps 6-8)
  //  hg  [64M,128M)     (reuses im tail/reT/imT)    (steps 7-8)
  char* ws = (char*)d_ws;
  bf16_t* w1b = (bf16_t*)(ws);
  bf16_t* w2b = (bf16_t*)(ws + (8u  << 20));
  float*  re  = (float*) (ws + (16u << 20));
  float*  im  = (float*) (ws + (48u << 20));
  float*  reT = (float*) (ws + (80u << 20));
  float*  imT = (float*) (ws + (98u << 20));
  float*  fT  = (float*) (ws + (16u << 20));
  float*  y   = (float*) (ws + (33u << 20));
  bf16_t* xn  = (bf16_t*)(ws + (16u << 20));
  bf16_t* hg  = (bf16_t*)(ws + (64u << 20));

  // 1. weight transposes + bf16 conversion
  transpose_to_bf16<<<dim3(DFF/32, HD/32), dim3(32, 8), 0, stream>>>(w1, w1b, HD, DFF);
  transpose_to_bf16<<<dim3(HD/32, DFF/32), dim3(32, 8), 0, stream>>>(w2, w2b, DFF, HD);

  // 2. FFT along h (writes h < HKEEP only)
  fft_h_kernel<<<NROWS, 256, 0, stream>>>(x, re, im);

  // 3. transpose re/im to [h][bs]
  transpose2_f32<<<dim3(HKEEP/32, NROWS/32), dim3(32, 8), 0, stream>>>(re, im, reT, imT);

  // 4. FFT along s per (h<=512, batch) column; real part out
  fft_s_col<<<dim3(513, 4), 256, 0, stream>>>(reT, imT, fT);

  // 5. untranspose + Hermitian mirror + residual add
  umadd_kernel<<<dim3(HD/32, NROWS/32), dim3(32, 8), 0, stream>>>(fT, x, y);

  // 6. LN1 -> bf16
  layernorm_k<true><<<NROWS, 256, 0, stream>>>(y, ln1w, ln1b, xn, nullptr);

  // 7./8. FFN (1D grids, XCD-swizzled inside the kernel)
  gemm_bf16_kernel<true><<<(DFF/128)*(NROWS/128), 256, 0, stream>>>(
      xn, w1b, b1, nullptr, hg, nullptr, NROWS, DFF, HD, DFF/128);
  gemm_bf16_kernel<false><<<(HD/128)*(NROWS/128), 256, 0, stream>>>(
      hg, w2b, b2, xn, nullptr, out, NROWS, HD, DFF, HD/128);

  // 9. LN2 in place on d_out
  layernorm_k<false><<<NROWS, 256, 0, stream>>>(out, ln2w, ln2b, nullptr, out);
}